// Round 1
// baseline (1134.750 us; speedup 1.0000x reference)
//
#include <hip/hip_runtime.h>
#include <hip/hip_bf16.h>

#define BD 4
#define SS 4096
#define DD 1024
#define RTOT (BD*SS)   // 16384 total rows

typedef __attribute__((ext_vector_type(8))) short bf16x8;
typedef __attribute__((ext_vector_type(4))) float f32x4;

static __device__ __forceinline__ unsigned short f2bf(float f) {
  unsigned int u = __float_as_uint(f);
  u += 0x7fff + ((u >> 16) & 1);   // round-to-nearest-even
  return (unsigned short)(u >> 16);
}
static __device__ __forceinline__ float bf2f(unsigned short h) {
  return __uint_as_float(((unsigned int)h) << 16);
}

// ---------------- split W into hi/lo bf16 ----------------
__global__ void split_w_kernel(const float* __restrict__ W,
                               unsigned short* __restrict__ Whi,
                               unsigned short* __restrict__ Wlo) {
  int i = (blockIdx.x * 256 + threadIdx.x) * 4;
  float4 x = *reinterpret_cast<const float4*>(W + i);
  ushort4 h, l;
  h.x = f2bf(x.x); l.x = f2bf(x.x - bf2f(h.x));
  h.y = f2bf(x.y); l.y = f2bf(x.y - bf2f(h.y));
  h.z = f2bf(x.z); l.z = f2bf(x.z - bf2f(h.z));
  h.w = f2bf(x.w); l.w = f2bf(x.w - bf2f(h.w));
  *reinterpret_cast<ushort4*>(Whi + i) = h;
  *reinterpret_cast<ushort4*>(Wlo + i) = l;
}

// ---------------- projection GEMM: P = X W^T + b ----------------
// MODE 0/1: write hi/lo bf16 row-major [row][o]   (q or k)
// MODE 2  : write v^T bf16   [b][o][s]            (for PV B-operand)
template<int MODE>
__global__ __launch_bounds__(256, 2)
void proj_kernel(const float* __restrict__ X,
                 const unsigned short* __restrict__ Wh,
                 const unsigned short* __restrict__ Wl,
                 const float* __restrict__ bias,
                 unsigned short* __restrict__ Ohi,
                 unsigned short* __restrict__ Olo)
{
  __shared__ unsigned short Ah[128][40], Al[128][40], Bh[128][40], Bl[128][40];
  const int tid = threadIdx.x;
  const int lane = tid & 63, wid = tid >> 6;
  const int m0 = blockIdx.x * 128;
  const int n0 = blockIdx.y * 128;
  const int wm = (wid >> 1) * 64, wn = (wid & 1) * 64;

  f32x4 acc[4][4] = {};

  for (int k0 = 0; k0 < DD; k0 += 32) {
    __syncthreads();
    // stage A: 128x32 fp32 -> hi/lo bf16
#pragma unroll
    for (int rnd = 0; rnd < 4; ++rnd) {
      int e = rnd * 256 + tid;
      int r = e >> 3, c = (e & 7) * 4;
      float4 x = *reinterpret_cast<const float4*>(X + (size_t)(m0 + r) * DD + k0 + c);
      ushort4 h, l;
      h.x = f2bf(x.x); l.x = f2bf(x.x - bf2f(h.x));
      h.y = f2bf(x.y); l.y = f2bf(x.y - bf2f(h.y));
      h.z = f2bf(x.z); l.z = f2bf(x.z - bf2f(h.z));
      h.w = f2bf(x.w); l.w = f2bf(x.w - bf2f(h.w));
      *reinterpret_cast<ushort4*>(&Ah[r][c]) = h;
      *reinterpret_cast<ushort4*>(&Al[r][c]) = l;
    }
    // stage B: pre-split W tiles (rows = output cols n, k contiguous)
#pragma unroll
    for (int rnd = 0; rnd < 2; ++rnd) {
      int e = rnd * 256 + tid;
      int r = e >> 2, c = (e & 3) * 8;
      *reinterpret_cast<uint4*>(&Bh[r][c]) =
        *reinterpret_cast<const uint4*>(Wh + (size_t)(n0 + r) * DD + k0 + c);
      *reinterpret_cast<uint4*>(&Bl[r][c]) =
        *reinterpret_cast<const uint4*>(Wl + (size_t)(n0 + r) * DD + k0 + c);
    }
    __syncthreads();

    bf16x8 ah[4], al[4], bh[4], bl[4];
    const int fr = lane & 15, kb = (lane >> 4) * 8;
#pragma unroll
    for (int i = 0; i < 4; ++i) {
      ah[i] = *reinterpret_cast<const bf16x8*>(&Ah[wm + i * 16 + fr][kb]);
      al[i] = *reinterpret_cast<const bf16x8*>(&Al[wm + i * 16 + fr][kb]);
      bh[i] = *reinterpret_cast<const bf16x8*>(&Bh[wn + i * 16 + fr][kb]);
      bl[i] = *reinterpret_cast<const bf16x8*>(&Bl[wn + i * 16 + fr][kb]);
    }
#pragma unroll
    for (int i = 0; i < 4; ++i)
#pragma unroll
      for (int j = 0; j < 4; ++j) {
        acc[i][j] = __builtin_amdgcn_mfma_f32_16x16x32_bf16(ah[i], bh[j], acc[i][j], 0, 0, 0);
        acc[i][j] = __builtin_amdgcn_mfma_f32_16x16x32_bf16(ah[i], bl[j], acc[i][j], 0, 0, 0);
        acc[i][j] = __builtin_amdgcn_mfma_f32_16x16x32_bf16(al[i], bh[j], acc[i][j], 0, 0, 0);
      }
  }

  // epilogue: C/D layout col=lane&15, row=(lane>>4)*4+reg
  const int col = lane & 15, rb = (lane >> 4) * 4;
#pragma unroll
  for (int i = 0; i < 4; ++i) {
#pragma unroll
    for (int j = 0; j < 4; ++j) {
      int oc = n0 + wn + j * 16 + col;
      float bv = bias[oc];
      if (MODE < 2) {
#pragma unroll
        for (int q = 0; q < 4; ++q) {
          int row = m0 + wm + i * 16 + rb + q;
          float p = acc[i][j][q] + bv;
          unsigned short h = f2bf(p);
          Ohi[(size_t)row * DD + oc] = h;
          Olo[(size_t)row * DD + oc] = f2bf(p - bf2f(h));
        }
      } else {
        int row = m0 + wm + i * 16 + rb;       // 4 consecutive s values
        int bb = row >> 12, s = row & (SS - 1);
        ushort4 h;
        h.x = f2bf(acc[i][j][0] + bv);
        h.y = f2bf(acc[i][j][1] + bv);
        h.z = f2bf(acc[i][j][2] + bv);
        h.w = f2bf(acc[i][j][3] + bv);
        *reinterpret_cast<ushort4*>(Ohi + ((size_t)(bb * DD + oc)) * SS + s) = h;
      }
    }
  }
}

// ---------------- logits GEMM: A[b,t,s] = sum_o q[t,o] k[s,o] (3-term split) ----------------
__global__ __launch_bounds__(256, 2)
void logits_kernel(const unsigned short* __restrict__ qh, const unsigned short* __restrict__ ql,
                   const unsigned short* __restrict__ kh, const unsigned short* __restrict__ kl,
                   float* __restrict__ out)
{
  __shared__ unsigned short Ah[128][40], Al[128][40], Bh[128][40], Bl[128][40];
  const int tid = threadIdx.x, lane = tid & 63, wid = tid >> 6;
  const int b = blockIdx.z;
  const int t0 = blockIdx.x * 128, s0 = blockIdx.y * 128;
  const unsigned short* qhB = qh + ((size_t)b * SS + t0) * DD;
  const unsigned short* qlB = ql + ((size_t)b * SS + t0) * DD;
  const unsigned short* khB = kh + ((size_t)b * SS + s0) * DD;
  const unsigned short* klB = kl + ((size_t)b * SS + s0) * DD;
  const int wm = (wid >> 1) * 64, wn = (wid & 1) * 64;

  f32x4 acc[4][4] = {};

  for (int k0 = 0; k0 < DD; k0 += 32) {
    __syncthreads();
#pragma unroll
    for (int rnd = 0; rnd < 2; ++rnd) {
      int e = rnd * 256 + tid;
      int r = e >> 2, c = (e & 3) * 8;
      *reinterpret_cast<uint4*>(&Ah[r][c]) = *reinterpret_cast<const uint4*>(qhB + (size_t)r * DD + k0 + c);
      *reinterpret_cast<uint4*>(&Al[r][c]) = *reinterpret_cast<const uint4*>(qlB + (size_t)r * DD + k0 + c);
      *reinterpret_cast<uint4*>(&Bh[r][c]) = *reinterpret_cast<const uint4*>(khB + (size_t)r * DD + k0 + c);
      *reinterpret_cast<uint4*>(&Bl[r][c]) = *reinterpret_cast<const uint4*>(klB + (size_t)r * DD + k0 + c);
    }
    __syncthreads();

    bf16x8 ah[4], al[4], bh[4], bl[4];
    const int fr = lane & 15, kb = (lane >> 4) * 8;
#pragma unroll
    for (int i = 0; i < 4; ++i) {
      ah[i] = *reinterpret_cast<const bf16x8*>(&Ah[wm + i * 16 + fr][kb]);
      al[i] = *reinterpret_cast<const bf16x8*>(&Al[wm + i * 16 + fr][kb]);
      bh[i] = *reinterpret_cast<const bf16x8*>(&Bh[wn + i * 16 + fr][kb]);
      bl[i] = *reinterpret_cast<const bf16x8*>(&Bl[wn + i * 16 + fr][kb]);
    }
#pragma unroll
    for (int i = 0; i < 4; ++i)
#pragma unroll
      for (int j = 0; j < 4; ++j) {
        acc[i][j] = __builtin_amdgcn_mfma_f32_16x16x32_bf16(ah[i], bh[j], acc[i][j], 0, 0, 0);
        acc[i][j] = __builtin_amdgcn_mfma_f32_16x16x32_bf16(ah[i], bl[j], acc[i][j], 0, 0, 0);
        acc[i][j] = __builtin_amdgcn_mfma_f32_16x16x32_bf16(al[i], bh[j], acc[i][j], 0, 0, 0);
      }
  }

  const int col = lane & 15, rb = (lane >> 4) * 4;
#pragma unroll
  for (int i = 0; i < 4; ++i)
#pragma unroll
    for (int j = 0; j < 4; ++j) {
      int s = s0 + wn + j * 16 + col;
#pragma unroll
      for (int q = 0; q < 4; ++q) {
        int t = t0 + wm + i * 16 + rb + q;
        out[((size_t)b * SS + t) * SS + s] = acc[i][j][q];
      }
    }
}

// ---------------- row softmax in-place ----------------
__global__ __launch_bounds__(256)
void softmax_kernel(float* __restrict__ attn) {
  float* rp = attn + (size_t)blockIdx.x * SS;
  const int tid = threadIdx.x, lane = tid & 63, wid = tid >> 6;
  float v[16];
  float m = -1e30f;
#pragma unroll
  for (int i = 0; i < 4; ++i) {
    float4 x = *reinterpret_cast<const float4*>(rp + i * 1024 + tid * 4);
    v[i * 4 + 0] = x.x; v[i * 4 + 1] = x.y; v[i * 4 + 2] = x.z; v[i * 4 + 3] = x.w;
    m = fmaxf(m, fmaxf(fmaxf(x.x, x.y), fmaxf(x.z, x.w)));
  }
#pragma unroll
  for (int off = 32; off; off >>= 1) m = fmaxf(m, __shfl_xor(m, off));
  __shared__ float redm[4], reds[4];
  if (lane == 0) redm[wid] = m;
  __syncthreads();
  m = fmaxf(fmaxf(redm[0], redm[1]), fmaxf(redm[2], redm[3]));
  float sum = 0.f;
#pragma unroll
  for (int i = 0; i < 16; ++i) { v[i] = __expf(v[i] - m); sum += v[i]; }
#pragma unroll
  for (int off = 32; off; off >>= 1) sum += __shfl_xor(sum, off);
  if (lane == 0) reds[wid] = sum;
  __syncthreads();
  float inv = 1.0f / (reds[0] + reds[1] + reds[2] + reds[3]);
#pragma unroll
  for (int i = 0; i < 4; ++i) {
    float4 x;
    x.x = v[i * 4 + 0] * inv; x.y = v[i * 4 + 1] * inv;
    x.z = v[i * 4 + 2] * inv; x.w = v[i * 4 + 3] * inv;
    *reinterpret_cast<float4*>(rp + i * 1024 + tid * 4) = x;
  }
}

// ---------------- PV GEMM: O[b,t,o] = sum_s attn[t,s] v[s,o] ----------------
__global__ __launch_bounds__(256, 2)
void pv_kernel(const float* __restrict__ attn, const unsigned short* __restrict__ vT,
               float* __restrict__ out)
{
  __shared__ unsigned short Ah[128][40], Bh[128][40];
  const int tid = threadIdx.x, lane = tid & 63, wid = tid >> 6;
  const int b = blockIdx.z, t0 = blockIdx.x * 128, n0 = blockIdx.y * 128;
  const float* aB = attn + (size_t)b * SS * SS;
  const unsigned short* vB = vT + ((size_t)b * DD + n0) * SS;
  const int wm = (wid >> 1) * 64, wn = (wid & 1) * 64;

  f32x4 acc[4][4] = {};

  for (int s0 = 0; s0 < SS; s0 += 32) {
    __syncthreads();
#pragma unroll
    for (int rnd = 0; rnd < 4; ++rnd) {
      int e = rnd * 256 + tid;
      int r = e >> 3, c = (e & 7) * 4;
      float4 x = *reinterpret_cast<const float4*>(aB + (size_t)(t0 + r) * SS + s0 + c);
      ushort4 h;
      h.x = f2bf(x.x); h.y = f2bf(x.y); h.z = f2bf(x.z); h.w = f2bf(x.w);
      *reinterpret_cast<ushort4*>(&Ah[r][c]) = h;
    }
#pragma unroll
    for (int rnd = 0; rnd < 2; ++rnd) {
      int e = rnd * 256 + tid;
      int r = e >> 2, c = (e & 3) * 8;
      *reinterpret_cast<uint4*>(&Bh[r][c]) = *reinterpret_cast<const uint4*>(vB + (size_t)r * SS + s0 + c);
    }
    __syncthreads();

    bf16x8 ah[4], bh[4];
    const int fr = lane & 15, kb = (lane >> 4) * 8;
#pragma unroll
    for (int i = 0; i < 4; ++i) {
      ah[i] = *reinterpret_cast<const bf16x8*>(&Ah[wm + i * 16 + fr][kb]);
      bh[i] = *reinterpret_cast<const bf16x8*>(&Bh[wn + i * 16 + fr][kb]);
    }
#pragma unroll
    for (int i = 0; i < 4; ++i)
#pragma unroll
      for (int j = 0; j < 4; ++j)
        acc[i][j] = __builtin_amdgcn_mfma_f32_16x16x32_bf16(ah[i], bh[j], acc[i][j], 0, 0, 0);
  }

  const int col = lane & 15, rb = (lane >> 4) * 4;
#pragma unroll
  for (int i = 0; i < 4; ++i)
#pragma unroll
    for (int j = 0; j < 4; ++j) {
      int o = n0 + wn + j * 16 + col;
#pragma unroll
      for (int q = 0; q < 4; ++q) {
        int t = t0 + wm + i * 16 + rb + q;
        out[((size_t)b * SS + t) * DD + o] = acc[i][j][q];
      }
    }
}

extern "C" void kernel_launch(void* const* d_in, const int* in_sizes, int n_in,
                              void* d_out, int out_size, void* d_ws, size_t ws_size,
                              hipStream_t stream) {
  const float* query = (const float*)d_in[0];
  const float* key   = (const float*)d_in[1];
  const float* value = (const float*)d_in[2];
  const float* W     = (const float*)d_in[3];
  const float* bias  = (const float*)d_in[4];

  float* out  = (float*)d_out;                       // [B,S,D]
  float* attn = out + (size_t)BD * SS * DD;          // [B,S,S]

  // workspace layout (bf16 elements): need ~164 MB
  unsigned short* Whi = (unsigned short*)d_ws;
  unsigned short* Wlo = Whi + (size_t)DD * DD;
  unsigned short* qhi = Wlo + (size_t)DD * DD;
  unsigned short* qlo = qhi + (size_t)RTOT * DD;
  unsigned short* khi = qlo + (size_t)RTOT * DD;
  unsigned short* klo = khi + (size_t)RTOT * DD;
  unsigned short* vT  = klo + (size_t)RTOT * DD;

  split_w_kernel<<<DD * DD / (256 * 4), 256, 0, stream>>>(W, Whi, Wlo);

  dim3 gp(RTOT / 128, DD / 128);
  proj_kernel<0><<<gp, 256, 0, stream>>>(query, Whi, Wlo, bias, qhi, qlo);
  proj_kernel<1><<<gp, 256, 0, stream>>>(key,   Whi, Wlo, bias, khi, klo);
  proj_kernel<2><<<gp, 256, 0, stream>>>(value, Whi, Wlo, bias, vT,  nullptr);

  logits_kernel<<<dim3(SS / 128, SS / 128, BD), 256, 0, stream>>>(qhi, qlo, khi, klo, attn);
  softmax_kernel<<<RTOT, 256, 0, stream>>>(attn);
  pv_kernel<<<dim3(SS / 128, DD / 128, BD), 256, 0, stream>>>(attn, vT, out);
}